// Round 8
// baseline (546.422 us; speedup 1.0000x reference)
//
#include <hip/hip_runtime.h>
#include <hip/hip_bf16.h>

typedef __attribute__((ext_vector_type(8))) short short8;
typedef __attribute__((ext_vector_type(4))) float f32x4;
typedef __attribute__((ext_vector_type(16))) float f32x16;
typedef __attribute__((ext_vector_type(4))) unsigned int u32x4;

#define NB 8
#define NC 256
#define NNN 4096
#define L2E 1.44269504088896f

__device__ __forceinline__ ushort f2bf(float f) {
  __hip_bfloat16 h = __float2bfloat16(f);
  return *reinterpret_cast<ushort*>(&h);
}
__device__ __forceinline__ unsigned pack2(float a, float b) {
  return (unsigned)f2bf(a) | ((unsigned)f2bf(b) << 16);
}
__device__ __forceinline__ void gload16(const void* g, void* l) {
  __builtin_amdgcn_global_load_lds(
      (const __attribute__((address_space(1))) void*)g,
      (__attribute__((address_space(3))) void*)l, 16, 0, 0);
}

// fTs: per batch, per 64-n tile: [32 c-chunks][64 n-rows][8 ushorts]
// fTs[b][n][c] at b*NNN*NC + (n>>6)*16384 + (c>>3)*512 + (n&63)*8 + (c&7)
__global__ __launch_bounds__(256) void prep_T(const float* __restrict__ x,
                                              ushort* __restrict__ fTs) {
  __shared__ float tile[32][33];
  const int tx = threadIdx.x, ty = threadIdx.y;
  const int n0 = blockIdx.x * 32, c0 = blockIdx.y * 32, b = blockIdx.z;
#pragma unroll
  for (int k = 0; k < 4; ++k) {
    tile[ty + 8 * k][tx] =
        x[((size_t)(b * NC + c0 + ty + 8 * k)) * NNN + n0 + tx];
  }
  __syncthreads();
#pragma unroll
  for (int k = 0; k < 4; ++k) {
    const int n = n0 + ty + 8 * k;
    const int c = c0 + tx;
    fTs[(size_t)b * NNN * NC + (size_t)(n >> 6) * 16384 + (c >> 3) * 512 +
        (n & 63) * 8 + (c & 7)] = f2bf(tile[tx][ty + 8 * k]);
  }
}

// fVs: per batch, per 64-m tile: [8 m-chunks][256 c][8 ushorts]
// value(b,c,m) at b*NNN*NC + (m>>6)*16384 + ((m&63)>>3)*2048 + c*8 + (m&7)
__global__ __launch_bounds__(256) void prep_V(const float* __restrict__ x,
                                              ushort* __restrict__ fVs) {
  __shared__ float vt[32][65];
  const int tx = threadIdx.x & 63;  // m within tile
  const int ty = threadIdx.x >> 6;  // 0..3
  const int t = blockIdx.x;         // m-tile
  const int cb = blockIdx.y;        // c-block of 32
  const int b = blockIdx.z;
  const float* xb = x + (size_t)b * NC * NNN;
#pragma unroll
  for (int j = 0; j < 8; ++j) {
    const int cl = ty + 4 * j;  // 0..31
    vt[cl][tx] = xb[(size_t)(cb * 32 + cl) * NNN + t * 64 + tx];
  }
  __syncthreads();
  const int c = threadIdx.x & 31;
  const int mc = threadIdx.x >> 5;  // 0..7
  short8 w;
#pragma unroll
  for (int e = 0; e < 8; ++e) w[e] = (short)f2bf(vt[c][mc * 8 + e]);
  *(short8*)(fVs + (size_t)b * NNN * NC + (size_t)t * 16384 + mc * 2048 +
             (cb * 32 + c) * 8) = w;
}

// Flash attention, 32x32x16 MFMA, swapped QK^T, O^T (n per-lane).
// 256 thr = 4 waves x 32 query cols, full 64-m tiles. Grid 256 (1 block/CU).
// LDS: dbuf 2x{K 32KB + V 32KB}. Conflict-free chunk-transposed layouts.
// Raw s_barrier + counted vmcnt pipeline (no vmcnt(0) drain in loop).
__global__ __launch_bounds__(256, 1) void attn_kernel(
    const float* __restrict__ x, const ushort* __restrict__ fTs,
    const ushort* __restrict__ fVs, const float* __restrict__ gamma,
    float* __restrict__ out) {
  __shared__ __align__(16) char smem[131072];

  const int tid = threadIdx.x;
  const int w = tid >> 6;
  const int l = tid & 63;
  const int l31 = l & 31;
  const int h = l >> 5;
  const int b = blockIdx.x & 7;             // batch -> XCD
  const int nt = blockIdx.x >> 3;           // n-tile (128 query rows)
  const int n0w = nt * 128 + w * 32;        // this wave's 32 query cols

  const char* fTb = (const char*)(fTs + (size_t)b * NNN * NC);
  const char* fVb = (const char*)(fVs + (size_t)b * NNN * NC);

  // Q fragments (B operand): col n = n0w+l31, k = kc*16+8h+j
  short8 q[16];
  {
    const int tq = n0w >> 6;
    const int rq = (n0w & 63) + l31;
    const char* qb = fTb + (size_t)tq * 32768 + rq * 16 + h * 1024;
#pragma unroll
    for (int kc = 0; kc < 16; ++kc)
      q[kc] = *(const short8*)(qb + kc * 2048);
  }

  // O^T accumulator: rows c = cf*32 + (r&3)+8*(r>>2)+4h, cols n = l31
  f32x16 o[8];
#pragma unroll
  for (int cf = 0; cf < 8; ++cf)
#pragma unroll
    for (int r = 0; r < 16; ++r) o[cf][r] = 0.f;
  float m_run = -3.0e38f, l_run = 0.f;

  // staging: linear 32KB block copies; per-lane src, wave-uniform dest+l*16
  const char* gK = fTb + w * 1024 + l * 16;
  const char* gV = fVb + w * 1024 + l * 16;
  const int ldW = w * 1024;

#define ISSK(tt, base)                                                    \
  {                                                                       \
    _Pragma("unroll") for (int j = 0; j < 8; ++j)                         \
        gload16(gK + (size_t)(tt)*32768 + j * 4096,                       \
                (base) + ldW + j * 4096);                                 \
  }
#define ISSV(tt, base)                                                    \
  {                                                                       \
    _Pragma("unroll") for (int j = 0; j < 8; ++j)                         \
        gload16(gV + (size_t)(tt)*32768 + j * 4096,                       \
                (base) + 32768 + ldW + j * 4096);                         \
  }

  ISSK(0, smem);
  __builtin_amdgcn_sched_barrier(0);
  ISSV(0, smem);
  __builtin_amdgcn_sched_barrier(0);

  for (int t = 0; t < 64; ++t) {
    char* bufC = smem + (t & 1) * 65536;
    char* bufN = smem + ((t + 1) & 1) * 65536;

    // K(t) ready (own 8 oldest loads), then block-wide
    asm volatile("s_waitcnt vmcnt(8)" ::: "memory");
    __builtin_amdgcn_sched_barrier(0);
    __builtin_amdgcn_s_barrier();
    __builtin_amdgcn_sched_barrier(0);
    if (t < 63) ISSK(t + 1, bufN);

    // ---- S^T = K * Q^T : two independent 16-chains, conflict-free reads ----
    f32x16 s0, s1;
#pragma unroll
    for (int r = 0; r < 16; ++r) { s0[r] = 0.f; s1[r] = 0.f; }
#pragma unroll
    for (int kc = 0; kc < 16; ++kc) {
      const char* ca = bufC + (2 * kc + h) * 1024;
      short8 ka0 = *(const short8*)(ca + l31 * 16);
      short8 ka1 = *(const short8*)(ca + 512 + l31 * 16);
      s0 = __builtin_amdgcn_mfma_f32_32x32x16_bf16(ka0, q[kc], s0, 0, 0, 0);
      s1 = __builtin_amdgcn_mfma_f32_32x32x16_bf16(ka1, q[kc], s1, 0, 0, 0);
    }

    // ---- online softmax; lane owns col n = l31 ----
    float tm = s0[0];
#pragma unroll
    for (int r = 1; r < 16; ++r) tm = fmaxf(tm, s0[r]);
#pragma unroll
    for (int r = 0; r < 16; ++r) tm = fmaxf(tm, s1[r]);
    tm = fmaxf(tm, __shfl_xor(tm, 32));

    if (__any(tm > m_run + 8.f)) {  // T13 defer-max
      const float mnew = fmaxf(m_run, tm);
      const float alpha = exp2f((m_run - mnew) * L2E);
      m_run = mnew;
      l_run *= alpha;
#pragma unroll
      for (int cf = 0; cf < 8; ++cf)
#pragma unroll
        for (int r = 0; r < 16; ++r) o[cf][r] *= alpha;  // lane-local
    }

    float rsum = 0.f;
#pragma unroll
    for (int r = 0; r < 16; ++r) {
      const float pv = exp2f((s0[r] - m_run) * L2E); s0[r] = pv; rsum += pv;
    }
#pragma unroll
    for (int r = 0; r < 16; ++r) {
      const float pv = exp2f((s1[r] - m_run) * L2E); s1[r] = pv; rsum += pv;
    }
    rsum += __shfl_xor(rsum, 32);
    l_run += rsum;

    // V(t) ready (own V loads = oldest 8 of {V(t), K(t+1)}), block-wide
    if (t < 63) {
      asm volatile("s_waitcnt vmcnt(8)" ::: "memory");
    } else {
      asm volatile("s_waitcnt vmcnt(0)" ::: "memory");
    }
    __builtin_amdgcn_sched_barrier(0);
    __builtin_amdgcn_s_barrier();
    __builtin_amdgcn_sched_barrier(0);
    if (t < 63) ISSV(t + 1, bufN);

    // ---- pack P, exchange m-quads with lane^32, PV: O^T += V^T * P ----
    const char* Vp = bufC + 32768;
#pragma unroll
    for (int sv = 0; sv < 2; ++sv) {
      const f32x16& s = sv ? s1 : s0;
      const int mcb = sv * 4;
#pragma unroll
      for (int ks = 0; ks < 2; ++ks) {
        const int ok = 8 * ks + 4 * h;
        const int os = 8 * ks + 4 * (1 - h);
        const unsigned uA = pack2(s[ok], s[ok + 1]);
        const unsigned uB = pack2(s[ok + 2], s[ok + 3]);
        const unsigned vA = pack2(s[os], s[os + 1]);
        const unsigned vB = pack2(s[os + 2], s[os + 3]);
        const unsigned xA = (unsigned)__shfl_xor((int)vA, 32);
        const unsigned xB = (unsigned)__shfl_xor((int)vB, 32);
        u32x4 fu;
        if (h == 0) { fu[0] = uA; fu[1] = uB; fu[2] = xA; fu[3] = xB; }
        else        { fu[0] = xA; fu[1] = xB; fu[2] = uA; fu[3] = uB; }
        const short8 pb = __builtin_bit_cast(short8, fu);
        const int mc = mcb + 2 * ks + h;
#pragma unroll
        for (int cf = 0; cf < 8; ++cf) {
          const short8 va =
              *(const short8*)(Vp + mc * 4096 + (cf * 32 + l31) * 16);
          o[cf] =
              __builtin_amdgcn_mfma_f32_32x32x16_bf16(va, pb, o[cf], 0, 0, 0);
        }
      }
    }
  }
#undef ISSK
#undef ISSV

  // ---- epilogue: normalize, direct coalesced stores (lane = n) ----
  const float sc = gamma[0] / l_run;
#pragma unroll
  for (int cf = 0; cf < 8; ++cf)
#pragma unroll
    for (int r = 0; r < 16; ++r) {
      const int c = cf * 32 + (r & 3) + 8 * (r >> 2) + 4 * h;
      const size_t gi = ((size_t)(b * NC + c)) * NNN + n0w + l31;
      out[gi] = o[cf][r] * sc + x[gi];
    }
}

extern "C" void kernel_launch(void* const* d_in, const int* in_sizes, int n_in,
                              void* d_out, int out_size, void* d_ws,
                              size_t ws_size, hipStream_t stream) {
  const float* x = (const float*)d_in[0];
  const float* gamma = (const float*)d_in[1];
  float* out = (float*)d_out;
  ushort* fTs = (ushort*)d_ws;                          // 16.78 MB
  ushort* fVs = fTs + (size_t)NB * NNN * NC;            // 16.78 MB

  dim3 pg(NNN / 32, NC / 32, NB);
  dim3 pb(32, 8, 1);
  prep_T<<<pg, pb, 0, stream>>>(x, fTs);
  prep_V<<<dim3(64, 8, NB), dim3(256), 0, stream>>>(x, fVs);

  attn_kernel<<<dim3(256), dim3(256), 0, stream>>>(x, fTs, fVs, gamma, out);
}

// Round 9
// 334.154 us; speedup vs baseline: 1.6352x; 1.6352x over previous
//
#include <hip/hip_runtime.h>
#include <hip/hip_bf16.h>

typedef __attribute__((ext_vector_type(8))) short short8;
typedef __attribute__((ext_vector_type(4))) float f32x4;
typedef __attribute__((ext_vector_type(16))) float f32x16;
typedef __attribute__((ext_vector_type(4))) unsigned int u32x4;

#define NB 8
#define NC 256
#define NNN 4096
#define L2E 1.44269504088896f

__device__ __forceinline__ ushort f2bf(float f) {
  __hip_bfloat16 h = __float2bfloat16(f);
  return *reinterpret_cast<ushort*>(&h);
}
__device__ __forceinline__ unsigned pack2(float a, float b) {
  return (unsigned)f2bf(a) | ((unsigned)f2bf(b) << 16);
}
__device__ __forceinline__ void gload16(const void* g, void* l) {
  __builtin_amdgcn_global_load_lds(
      (const __attribute__((address_space(1))) void*)g,
      (__attribute__((address_space(3))) void*)l, 16, 0, 0);
}

// fTs: per batch, per 64-n tile: [32 c-chunks][64 n-rows][8 ushorts]
// fTs[b][n][c] at b*NNN*NC + (n>>6)*16384 + (c>>3)*512 + (n&63)*8 + (c&7)
__global__ __launch_bounds__(256) void prep_T(const float* __restrict__ x,
                                              ushort* __restrict__ fTs) {
  __shared__ float tile[32][33];
  const int tx = threadIdx.x, ty = threadIdx.y;
  const int n0 = blockIdx.x * 32, c0 = blockIdx.y * 32, b = blockIdx.z;
#pragma unroll
  for (int k = 0; k < 4; ++k) {
    tile[ty + 8 * k][tx] =
        x[((size_t)(b * NC + c0 + ty + 8 * k)) * NNN + n0 + tx];
  }
  __syncthreads();
#pragma unroll
  for (int k = 0; k < 4; ++k) {
    const int n = n0 + ty + 8 * k;
    const int c = c0 + tx;
    fTs[(size_t)b * NNN * NC + (size_t)(n >> 6) * 16384 + (c >> 3) * 512 +
        (n & 63) * 8 + (c & 7)] = f2bf(tile[tx][ty + 8 * k]);
  }
}

// fVs: per batch, per 64-m tile: [8 m-chunks][256 c][8 ushorts]
// value(b,c,m) at b*NNN*NC + (m>>6)*16384 + ((m&63)>>3)*2048 + c*8 + (m&7)
__global__ __launch_bounds__(256) void prep_V(const float* __restrict__ x,
                                              ushort* __restrict__ fVs) {
  __shared__ float vt[32][65];
  const int tx = threadIdx.x & 63;  // m within tile
  const int ty = threadIdx.x >> 6;  // 0..3
  const int t = blockIdx.x;         // m-tile
  const int cb = blockIdx.y;        // c-block of 32
  const int b = blockIdx.z;
  const float* xb = x + (size_t)b * NC * NNN;
#pragma unroll
  for (int j = 0; j < 8; ++j) {
    const int cl = ty + 4 * j;  // 0..31
    vt[cl][tx] = xb[(size_t)(cb * 32 + cl) * NNN + t * 64 + tx];
  }
  __syncthreads();
  const int c = threadIdx.x & 31;
  const int mc = threadIdx.x >> 5;  // 0..7
  short8 w;
#pragma unroll
  for (int e = 0; e < 8; ++e) w[e] = (short)f2bf(vt[c][mc * 8 + e]);
  *(short8*)(fVs + (size_t)b * NNN * NC + (size_t)t * 16384 + mc * 2048 +
             (cb * 32 + c) * 8) = w;
}

// Flash attention, 32x32x16 MFMA, swapped QK^T, O^T (n per-lane).
// 256 thr = 4 waves x 32 query cols, full 64-m tiles. Grid 256 (1 block/CU).
// LDS: dbuf 2x{K 32KB + V 32KB}, conflict-free chunk-transposed layouts.
// R4-style pipeline: issue DMA(t+1), compute(t), one __syncthreads per tile.
__global__ __launch_bounds__(256, 1) void attn_kernel(
    const float* __restrict__ x, const ushort* __restrict__ fTs,
    const ushort* __restrict__ fVs, const float* __restrict__ gamma,
    float* __restrict__ out) {
  __shared__ __align__(16) char smem[131072];

  const int tid = threadIdx.x;
  const int w = tid >> 6;
  const int l = tid & 63;
  const int l31 = l & 31;
  const int h = l >> 5;
  const int b = blockIdx.x & 7;       // batch -> XCD
  const int nt = blockIdx.x >> 3;     // n-tile (128 query rows)
  const int n0w = nt * 128 + w * 32;  // this wave's 32 query cols

  const char* fTb = (const char*)(fTs + (size_t)b * NNN * NC);
  const char* fVb = (const char*)(fVs + (size_t)b * NNN * NC);

  // Q fragments (B operand): col n = n0w+l31, k = kc*16+8h+j
  short8 q[16];
  {
    const int tq = n0w >> 6;
    const int rq = (n0w & 63) + l31;
    const char* qb = fTb + (size_t)tq * 32768 + rq * 16 + h * 1024;
#pragma unroll
    for (int kc = 0; kc < 16; ++kc) q[kc] = *(const short8*)(qb + kc * 2048);
  }

  // O^T accumulator: rows c = cf*32 + (r&3)+8*(r>>2)+4h, cols n = l31
  f32x16 o[8];
#pragma unroll
  for (int cf = 0; cf < 8; ++cf)
#pragma unroll
    for (int r = 0; r < 16; ++r) o[cf][r] = 0.f;
  float m_run = -3.0e38f, l_run = 0.f;

  // staging: linear 32KB block copies; per-lane src, wave-uniform dest+l*16
  const char* gK = fTb + w * 1024 + l * 16;
  const char* gV = fVb + w * 1024 + l * 16;
  const int ldW = w * 1024;

#define STAGE(tt, base)                                                     \
  {                                                                         \
    _Pragma("unroll") for (int j = 0; j < 8; ++j)                           \
        gload16(gK + (size_t)(tt) * 32768 + j * 4096,                       \
                (base) + ldW + j * 4096);                                   \
    _Pragma("unroll") for (int j = 0; j < 8; ++j)                           \
        gload16(gV + (size_t)(tt) * 32768 + j * 4096,                       \
                (base) + 32768 + ldW + j * 4096);                           \
  }

  STAGE(0, smem);
  __syncthreads();

  for (int t = 0; t < 64; ++t) {
    char* bufC = smem + (t & 1) * 65536;
    if (t < 63) {  // issue next tile's DMA; lands during this tile's compute
      char* bufN = smem + ((t + 1) & 1) * 65536;
      STAGE(t + 1, bufN);
    }

    // ---- S^T = K * Q^T : two independent 16-chains, conflict-free reads ----
    f32x16 s0, s1;
#pragma unroll
    for (int r = 0; r < 16; ++r) { s0[r] = 0.f; s1[r] = 0.f; }
#pragma unroll
    for (int kc = 0; kc < 16; ++kc) {
      const char* ca = bufC + (2 * kc + h) * 1024;
      short8 ka0 = *(const short8*)(ca + l31 * 16);
      short8 ka1 = *(const short8*)(ca + 512 + l31 * 16);
      s0 = __builtin_amdgcn_mfma_f32_32x32x16_bf16(ka0, q[kc], s0, 0, 0, 0);
      s1 = __builtin_amdgcn_mfma_f32_32x32x16_bf16(ka1, q[kc], s1, 0, 0, 0);
    }

    // ---- online softmax; lane owns col n = l31 ----
    float tm = s0[0];
#pragma unroll
    for (int r = 1; r < 16; ++r) tm = fmaxf(tm, s0[r]);
#pragma unroll
    for (int r = 0; r < 16; ++r) tm = fmaxf(tm, s1[r]);
    tm = fmaxf(tm, __shfl_xor(tm, 32));

    if (__any(tm > m_run + 8.f)) {  // T13 defer-max
      const float mnew = fmaxf(m_run, tm);
      const float alpha = exp2f((m_run - mnew) * L2E);
      m_run = mnew;
      l_run *= alpha;
#pragma unroll
      for (int cf = 0; cf < 8; ++cf)
#pragma unroll
        for (int r = 0; r < 16; ++r) o[cf][r] *= alpha;  // lane-local
    }

    float rsum = 0.f;
#pragma unroll
    for (int r = 0; r < 16; ++r) {
      const float pv = exp2f((s0[r] - m_run) * L2E); s0[r] = pv; rsum += pv;
    }
#pragma unroll
    for (int r = 0; r < 16; ++r) {
      const float pv = exp2f((s1[r] - m_run) * L2E); s1[r] = pv; rsum += pv;
    }
    rsum += __shfl_xor(rsum, 32);
    l_run += rsum;

    // ---- pack P, exchange m-quads with lane^32, PV: O^T += V^T * P ----
    const char* Vp = bufC + 32768;
#pragma unroll
    for (int sv = 0; sv < 2; ++sv) {
      const f32x16& s = sv ? s1 : s0;
      const int mcb = sv * 4;
#pragma unroll
      for (int ks = 0; ks < 2; ++ks) {
        const int ok = 8 * ks + 4 * h;
        const int os = 8 * ks + 4 * (1 - h);
        const unsigned uA = pack2(s[ok], s[ok + 1]);
        const unsigned uB = pack2(s[ok + 2], s[ok + 3]);
        const unsigned vA = pack2(s[os], s[os + 1]);
        const unsigned vB = pack2(s[os + 2], s[os + 3]);
        const unsigned xA = (unsigned)__shfl_xor((int)vA, 32);
        const unsigned xB = (unsigned)__shfl_xor((int)vB, 32);
        u32x4 fu;
        if (h == 0) { fu[0] = uA; fu[1] = uB; fu[2] = xA; fu[3] = xB; }
        else        { fu[0] = xA; fu[1] = xB; fu[2] = uA; fu[3] = uB; }
        const short8 pb = __builtin_bit_cast(short8, fu);
        const int mc = mcb + 2 * ks + h;
#pragma unroll
        for (int cf = 0; cf < 8; ++cf) {
          const short8 va =
              *(const short8*)(Vp + mc * 4096 + (cf * 32 + l31) * 16);
          o[cf] =
              __builtin_amdgcn_mfma_f32_32x32x16_bf16(va, pb, o[cf], 0, 0, 0);
        }
      }
    }
    __syncthreads();  // reads done; next tile's DMA drained
  }
#undef STAGE

  // ---- epilogue: normalize, direct coalesced stores (lane = n) ----
  const float sc = gamma[0] / l_run;
#pragma unroll
  for (int cf = 0; cf < 8; ++cf)
#pragma unroll
    for (int r = 0; r < 16; ++r) {
      const int c = cf * 32 + (r & 3) + 8 * (r >> 2) + 4 * h;
      const size_t gi = ((size_t)(b * NC + c)) * NNN + n0w + l31;
      out[gi] = o[cf][r] * sc + x[gi];
    }
}

extern "C" void kernel_launch(void* const* d_in, const int* in_sizes, int n_in,
                              void* d_out, int out_size, void* d_ws,
                              size_t ws_size, hipStream_t stream) {
  const float* x = (const float*)d_in[0];
  const float* gamma = (const float*)d_in[1];
  float* out = (float*)d_out;
  ushort* fTs = (ushort*)d_ws;                // 16.78 MB
  ushort* fVs = fTs + (size_t)NB * NNN * NC;  // 16.78 MB

  dim3 pg(NNN / 32, NC / 32, NB);
  dim3 pb(32, 8, 1);
  prep_T<<<pg, pb, 0, stream>>>(x, fTs);
  prep_V<<<dim3(64, 8, NB), dim3(256), 0, stream>>>(x, fVs);

  attn_kernel<<<dim3(256), dim3(256), 0, stream>>>(x, fTs, fVs, gamma, out);
}